// Round 11
// baseline (343.284 us; speedup 1.0000x reference)
//
#include <hip/hip_runtime.h>
#include <hip/hip_fp16.h>

#define B_ 64
#define N_ 4096
#define C_ 10
#define D_ 8
#define E_ 16
#define EPS_ 1e-7f
#define NT_ 8
#define NBLK_ (N_ / NT_)          // 512 pass blocks
#define NSLOT_ (NBLK_ * 2)        // 1024 partial slots (2 per block)
#define XSTR_ 12                  // padded x row stride (f32)
#define PROW_ 80                  // u32 per partial row (160 halfs)
#define WBROW_ 82                 // padded LDS writeback row stride (u32)

__device__ inline unsigned rne16(float f) {   // f32 -> bf16 round-nearest-even
    unsigned u = __float_as_uint(f);
    return (u + 0x7fffu + ((u >> 16) & 1u)) >> 16;
}
__device__ inline float plo(unsigned u) { return __uint_as_float(u << 16); }
__device__ inline float phi(unsigned u) { return __uint_as_float(u & 0xffff0000u); }
__device__ inline unsigned pk2(float a, float b) {   // bf16 trunc pack
    return (__float_as_uint(a) >> 16) | (__float_as_uint(b) & 0xffff0000u);
}
__device__ inline unsigned hpack(float a, float b) {
    __half2 t = __floats2half2_rn(a, b);
    return *(unsigned*)&t;
}
__device__ inline float2 hunpack(unsigned u) {
    return __half22float2(*(const __half2*)&u);
}

// Block: 512 thr = 8 waves = (h: b-half) x (np: 4 n-groups of 2 n).
// Thread owns TWO b (b0 = h*32+bl, b1 = b0+16). W staged as bf16 uint4
// granules [n][c][d2][eq]: one ds_read_b128 = 2d x 4e = 16 FMAs (40 reads/n
// vs 80 in f32 layout). x staged in LDS (padded). np pairs (0,1) and (2,3)
// combine into 2 fp16 partial slots per block.
// Static LDS: 20480 (W) + 24576 (x) = 45056 B; wb (41984 B) aliases it.
template <bool UNIFORM>
__global__ __launch_bounds__(512, 2) void caps_pass(
    const float* __restrict__ x, const float* __restrict__ W,
    const float* __restrict__ v_cum, unsigned* __restrict__ partial)
{
    __shared__ __align__(16) char smem[45056];
    uint4*    wlds = (uint4*)smem;                  // 1280 uint4 = 20480 B
    float*    xlds = (float*)(smem + 20480);        // 8n*64b*12 f32 = 24576 B
    unsigned* wb   = (unsigned*)smem;               // [2][64][WBROW_] alias

    const int tid = (int)threadIdx.x;
    const int blk = (int)blockIdx.x;
    const int n0  = blk * NT_;

    // ---- stage W -> LDS bf16 swizzled [n][c][d2][eq]{d&1 dword-pair} ----
    {
        const float4* wg = (const float4*)W + (size_t)blk * (NT_ * 320);
#pragma unroll
        for (int k = 0; k < 5; ++k) {
            const int f = k * 512 + tid;          // [0, 2560)
            const float4 v = wg[f];
            const int n    = f / 320;
            const int rem  = f - n * 320;
            const int c    = rem >> 5;
            const int rem2 = rem & 31;
            const int d    = rem2 >> 2;
            const int eqs  = rem2 & 3;
            unsigned* dst = (unsigned*)&wlds[((n * C_ + c) * 4 + (d >> 1)) * 4 + eqs]
                          + (d & 1) * 2;
            dst[0] = rne16(v.x) | (rne16(v.y) << 16);
            dst[1] = rne16(v.z) | (rne16(v.w) << 16);
        }
    }
    // ---- stage x -> LDS [n][b][XSTR_] fp32 ----
    {
        const float4* xg = (const float4*)x;
#pragma unroll
        for (int k = 0; k < 2; ++k) {
            const int g = k * 512 + tid;          // [0, 1024)
            const int b = g >> 4;
            const int r = g & 15;
            const int n = r >> 1;
            const int dq = r & 1;
            const float4 v = xg[((size_t)b * N_ + n0 + n) * 2 + dq];
            *(float4*)&xlds[(n * B_ + b) * XSTR_ + dq * 4] = v;
        }
    }
    __syncthreads();

    const int wv   = tid >> 6;
    const int lane = tid & 63;
    const int eq   = lane & 3;
    const int bl   = lane >> 2;
    const int h    = wv & 1;
    const int np   = wv >> 1;          // 0..3
    const int b0   = h * 32 + bl;
    const int b1   = b0 + 16;

    unsigned vcp0[C_][2], vcp1[C_][2];
    if (!UNIFORM) {
#pragma unroll
        for (int c = 0; c < C_; ++c) {
            const float4 a = *(const float4*)(v_cum + (b0 * C_ + c) * E_ + eq * 4);
            vcp0[c][0] = pk2(a.x, a.y); vcp0[c][1] = pk2(a.z, a.w);
            const float4 d = *(const float4*)(v_cum + (b1 * C_ + c) * E_ + eq * 4);
            vcp1[c][0] = pk2(d.x, d.y); vcp1[c][1] = pk2(d.z, d.w);
        }
    }

    float4 acc0[C_], acc1[C_];
#pragma unroll
    for (int c = 0; c < C_; ++c) {
        acc0[c] = make_float4(0.f, 0.f, 0.f, 0.f);
        acc1[c] = make_float4(0.f, 0.f, 0.f, 0.f);
    }

#pragma unroll 1
    for (int j = 0; j < 2; ++j) {
        const int nl = np * 2 + j;
        const float4 xa0 = *(const float4*)&xlds[(nl * B_ + b0) * XSTR_];
        const float4 xa1 = *(const float4*)&xlds[(nl * B_ + b0) * XSTR_ + 4];
        const float4 xb0 = *(const float4*)&xlds[(nl * B_ + b1) * XSTR_];
        const float4 xb1 = *(const float4*)&xlds[(nl * B_ + b1) * XSTR_ + 4];
        const float xv0[D_] = {xa0.x, xa0.y, xa0.z, xa0.w, xa1.x, xa1.y, xa1.z, xa1.w};
        const float xv1[D_] = {xb0.x, xb0.y, xb0.z, xb0.w, xb1.x, xb1.y, xb1.z, xb1.w};
        const uint4* wn = &wlds[nl * (C_ * 16)];

        if (UNIFORM) {
#pragma unroll
            for (int c = 0; c < C_; ++c) {
#pragma unroll
                for (int d2 = 0; d2 < 4; ++d2) {
                    const uint4 q = wn[c * 16 + d2 * 4 + eq];
                    const float a0 = xv0[2 * d2], a1 = xv0[2 * d2 + 1];
                    const float c0 = xv1[2 * d2], c1 = xv1[2 * d2 + 1];
                    acc0[c].x = fmaf(a0, plo(q.x), fmaf(a1, plo(q.z), acc0[c].x));
                    acc0[c].y = fmaf(a0, phi(q.x), fmaf(a1, phi(q.z), acc0[c].y));
                    acc0[c].z = fmaf(a0, plo(q.y), fmaf(a1, plo(q.w), acc0[c].z));
                    acc0[c].w = fmaf(a0, phi(q.y), fmaf(a1, phi(q.w), acc0[c].w));
                    acc1[c].x = fmaf(c0, plo(q.x), fmaf(c1, plo(q.z), acc1[c].x));
                    acc1[c].y = fmaf(c0, phi(q.x), fmaf(c1, phi(q.z), acc1[c].y));
                    acc1[c].z = fmaf(c0, plo(q.y), fmaf(c1, plo(q.w), acc1[c].z));
                    acc1[c].w = fmaf(c0, phi(q.y), fmaf(c1, phi(q.w), acc1[c].w));
                }
            }
        } else {
            unsigned uhp0[C_][2], uhp1[C_][2];
            float wgt0[C_], wgt1[C_];
#pragma unroll
            for (int c = 0; c < C_; ++c) {
                float4 u0 = make_float4(0.f, 0.f, 0.f, 0.f);
                float4 u1 = make_float4(0.f, 0.f, 0.f, 0.f);
#pragma unroll
                for (int d2 = 0; d2 < 4; ++d2) {
                    const uint4 q = wn[c * 16 + d2 * 4 + eq];
                    const float a0 = xv0[2 * d2], a1 = xv0[2 * d2 + 1];
                    const float c0 = xv1[2 * d2], c1 = xv1[2 * d2 + 1];
                    u0.x = fmaf(a0, plo(q.x), fmaf(a1, plo(q.z), u0.x));
                    u0.y = fmaf(a0, phi(q.x), fmaf(a1, phi(q.z), u0.y));
                    u0.z = fmaf(a0, plo(q.y), fmaf(a1, plo(q.w), u0.z));
                    u0.w = fmaf(a0, phi(q.y), fmaf(a1, phi(q.w), u0.w));
                    u1.x = fmaf(c0, plo(q.x), fmaf(c1, plo(q.z), u1.x));
                    u1.y = fmaf(c0, phi(q.x), fmaf(c1, phi(q.z), u1.y));
                    u1.z = fmaf(c0, plo(q.y), fmaf(c1, plo(q.w), u1.z));
                    u1.w = fmaf(c0, phi(q.y), fmaf(c1, phi(q.w), u1.w));
                }
                float t0 = u0.x * plo(vcp0[c][0]);
                t0 = fmaf(u0.y, phi(vcp0[c][0]), t0);
                t0 = fmaf(u0.z, plo(vcp0[c][1]), t0);
                t0 = fmaf(u0.w, phi(vcp0[c][1]), t0);
                t0 += __shfl_xor(t0, 1); t0 += __shfl_xor(t0, 2);
                wgt0[c] = t0;
                float t1 = u1.x * plo(vcp1[c][0]);
                t1 = fmaf(u1.y, phi(vcp1[c][0]), t1);
                t1 = fmaf(u1.z, plo(vcp1[c][1]), t1);
                t1 = fmaf(u1.w, phi(vcp1[c][1]), t1);
                t1 += __shfl_xor(t1, 1); t1 += __shfl_xor(t1, 2);
                wgt1[c] = t1;
                uhp0[c][0] = pk2(u0.x, u0.y); uhp0[c][1] = pk2(u0.z, u0.w);
                uhp1[c][0] = pk2(u1.x, u1.y); uhp1[c][1] = pk2(u1.z, u1.w);
            }
            // softmax over C, no max-sub (logits bounded, exp safe in f32)
            float s0 = 0.f, s1 = 0.f;
#pragma unroll
            for (int c = 0; c < C_; ++c) {
                wgt0[c] = __expf(wgt0[c]); s0 += wgt0[c];
                wgt1[c] = __expf(wgt1[c]); s1 += wgt1[c];
            }
            const float i0 = 1.f / s0, i1 = 1.f / s1;
#pragma unroll
            for (int c = 0; c < C_; ++c) {
                const float g0 = wgt0[c] * i0, g1 = wgt1[c] * i1;
                acc0[c].x = fmaf(g0, plo(uhp0[c][0]), acc0[c].x);
                acc0[c].y = fmaf(g0, phi(uhp0[c][0]), acc0[c].y);
                acc0[c].z = fmaf(g0, plo(uhp0[c][1]), acc0[c].z);
                acc0[c].w = fmaf(g0, phi(uhp0[c][1]), acc0[c].w);
                acc1[c].x = fmaf(g1, plo(uhp1[c][0]), acc1[c].x);
                acc1[c].y = fmaf(g1, phi(uhp1[c][0]), acc1[c].y);
                acc1[c].z = fmaf(g1, plo(uhp1[c][1]), acc1[c].z);
                acc1[c].w = fmaf(g1, phi(uhp1[c][1]), acc1[c].w);
            }
        }
    }

    const float fold = UNIFORM ? 0.1f : 1.f;   // softmax(0) = 1/10 folded out

    __syncthreads();   // all W/x LDS reads done; smem becomes wb buffer

    unsigned* wbh = wb + (np >> 1) * (B_ * WBROW_);
    if (np & 1) {      // np = 1,3 deposit folded fp16 partials
#pragma unroll
        for (int c = 0; c < C_; ++c) {
            *(uint2*)&wbh[b0 * WBROW_ + c * 8 + eq * 2] =
                make_uint2(hpack(acc0[c].x * fold, acc0[c].y * fold),
                           hpack(acc0[c].z * fold, acc0[c].w * fold));
            *(uint2*)&wbh[b1 * WBROW_ + c * 8 + eq * 2] =
                make_uint2(hpack(acc1[c].x * fold, acc1[c].y * fold),
                           hpack(acc1[c].z * fold, acc1[c].w * fold));
        }
    }
    __syncthreads();
    if (!(np & 1)) {   // np = 0,2 add their half and repack
#pragma unroll
        for (int c = 0; c < C_; ++c) {
            uint2 p0 = *(uint2*)&wbh[b0 * WBROW_ + c * 8 + eq * 2];
            const float2 a0 = hunpack(p0.x), a1 = hunpack(p0.y);
            p0.x = hpack(a0.x + acc0[c].x * fold, a0.y + acc0[c].y * fold);
            p0.y = hpack(a1.x + acc0[c].z * fold, a1.y + acc0[c].w * fold);
            *(uint2*)&wbh[b0 * WBROW_ + c * 8 + eq * 2] = p0;
            uint2 p1 = *(uint2*)&wbh[b1 * WBROW_ + c * 8 + eq * 2];
            const float2 d0 = hunpack(p1.x), d1 = hunpack(p1.y);
            p1.x = hpack(d0.x + acc1[c].x * fold, d0.y + acc1[c].y * fold);
            p1.y = hpack(d1.x + acc1[c].z * fold, d1.y + acc1[c].w * fold);
            *(uint2*)&wbh[b1 * WBROW_ + c * 8 + eq * 2] = p1;
        }
    }
    __syncthreads();

    // full-line coalesced write-out: 5120 uint2 by 512 threads (2 slots)
#pragma unroll
    for (int it = 0; it < 10; ++it) {
        const int i2   = it * 512 + tid;       // [0, 5120)
        const int r    = i2 / 40;              // [0, 128): half(1b) x b(6b)
        const int col2 = i2 - r * 40;
        const int half = r >> 6;
        const int bb   = r & 63;
        const int slot = blk * 2 + half;
        *(uint2*)(partial + ((size_t)bb * NSLOT_ + slot) * PROW_ + col2 * 2) =
            *(const uint2*)&wb[(half * B_ + bb) * WBROW_ + col2 * 2];
    }
}

// Block per b: sum partial[b][*][col] (fp16x2 rows, coalesced), squash, update.
// mode: 0 = v_cum = v, 1 = v_cum += v, 2 = out = v
__global__ __launch_bounds__(192) void caps_reduce(
    const unsigned* __restrict__ partial, float* __restrict__ v_cum,
    float* __restrict__ out, int mode)
{
    const int b = (int)blockIdx.x;
    const int tid = (int)threadIdx.x;
    __shared__ float redlo[2][PROW_], redhi[2][PROW_];
    if (tid < 2 * PROW_) {
        const int col = tid % PROW_;
        const int gh  = tid / PROW_;
        const unsigned* base =
            partial + ((size_t)b * NSLOT_ + (size_t)gh * (NSLOT_ / 2)) * PROW_ + col;
        float a0 = 0.f, a1 = 0.f, c0 = 0.f, c1 = 0.f;
        for (int k = 0; k < NSLOT_ / 2; k += 2) {
            const unsigned u0 = base[(size_t)k * PROW_];
            const unsigned u1 = base[(size_t)(k + 1) * PROW_];
            const float2 f0 = hunpack(u0);
            const float2 f1 = hunpack(u1);
            a0 += f0.x; c0 += f0.y;
            a1 += f1.x; c1 += f1.y;
        }
        redlo[gh][col] = a0 + a1;
        redhi[gh][col] = c0 + c1;
    }
    __syncthreads();
    if (tid < PROW_) {
        const float slo = redlo[0][tid] + redlo[1][tid];
        const float shi = redhi[0][tid] + redhi[1][tid];
        float p = slo * slo + shi * shi;
        p += __shfl_xor(p, 1); p += __shfl_xor(p, 2); p += __shfl_xor(p, 4);
        const float sc = (p / (1.f + p)) * rsqrtf(p + EPS_);
        const float v0 = sc * slo, v1 = sc * shi;
        const int o = b * (C_ * E_) + tid * 2;
        if (mode == 2)      { out[o] = v0;    out[o + 1] = v1; }
        else if (mode == 0) { v_cum[o] = v0;  v_cum[o + 1] = v1; }
        else                { v_cum[o] += v0; v_cum[o + 1] += v1; }
    }
}

extern "C" void kernel_launch(void* const* d_in, const int* in_sizes, int n_in,
                              void* d_out, int out_size, void* d_ws, size_t ws_size,
                              hipStream_t stream) {
    const float* x = (const float*)d_in[0];
    const float* W = (const float*)d_in[1];
    float* out = (float*)d_out;

    unsigned* partial = (unsigned*)d_ws;   // 64*1024*80*4 = 20.97 MB
    float* v_cum = (float*)((char*)d_ws +
        (size_t)B_ * NSLOT_ * PROW_ * sizeof(unsigned));

    for (int t = 0; t < 3; ++t) {
        if (t == 0)
            caps_pass<true ><<<dim3(NBLK_), 512, 0, stream>>>(x, W, v_cum, partial);
        else
            caps_pass<false><<<dim3(NBLK_), 512, 0, stream>>>(x, W, v_cum, partial);
        caps_reduce<<<dim3(B_), 192, 0, stream>>>(partial, v_cum, out, t);
    }
}

// Round 12
// 137.144 us; speedup vs baseline: 2.5031x; 2.5031x over previous
//
#include <hip/hip_runtime.h>
#include <hip/hip_fp16.h>

#define B_ 64
#define N_ 4096
#define C_ 10
#define D_ 8
#define E_ 16
#define EPS_ 1e-7f
#define NT_ 8
#define NBLK_ (N_ / NT_)          // 512 pass blocks
#define NSLOT_ (NBLK_ * 2)        // 1024 partial slots (2 per block)
#define XSTR_ 12                  // padded x row stride (f32)
#define PROW_ 80                  // u32 per partial row (160 halfs)

__device__ inline unsigned rne16(float f) {   // f32 -> bf16 round-nearest-even
    unsigned u = __float_as_uint(f);
    return (u + 0x7fffu + ((u >> 16) & 1u)) >> 16;
}
__device__ inline float plo(unsigned u) { return __uint_as_float(u << 16); }
__device__ inline float phi(unsigned u) { return __uint_as_float(u & 0xffff0000u); }
__device__ inline unsigned pk2(float a, float b) {   // bf16 trunc pack
    return (__float_as_uint(a) >> 16) | (__float_as_uint(b) & 0xffff0000u);
}
__device__ inline unsigned hpack(float a, float b) {
    __half2 t = __floats2half2_rn(a, b);
    return *(unsigned*)&t;
}
__device__ inline float2 hunpack(unsigned u) {
    return __half22float2(*(const __half2*)&u);
}

// Block: 256 thr = 4 waves = (h: b-half) x (np: n-half of 4 n each).
// Thread owns TWO b (b0 = h*32+bl, b1 = b0+16). W staged as bf16 uint4
// granules [n][c][d2][eq]: one ds_read_b128 = 2d x 4e = 16 FMAs per b.
// x staged in LDS (padded stride 12). Each np-wave-pair writes its own fp16
// partial slot directly (no LDS combine). launch_bounds(256,1): VGPR cap 512
// so the ~220-reg live set does NOT spill (R8-R11 all spilled at cap 128).
template <bool UNIFORM>
__global__ __launch_bounds__(256, 1) void caps_pass(
    const float* __restrict__ x, const float* __restrict__ W,
    const float* __restrict__ v_cum, unsigned* __restrict__ partial)
{
    __shared__ uint4 wlds[NT_ * C_ * 16];     // 1280 uint4 = 20480 B
    __shared__ float xlds[NT_ * B_ * XSTR_];  // 24576 B   (total 45056 B)

    const int tid = (int)threadIdx.x;
    const int blk = (int)blockIdx.x;
    const int n0  = blk * NT_;

    // ---- stage W -> LDS bf16 swizzled [n][c][d2][eq]{d&1 dword-pair} ----
    {
        const float4* wg = (const float4*)W + (size_t)blk * (NT_ * 320);
#pragma unroll
        for (int k = 0; k < 10; ++k) {
            const int f = k * 256 + tid;          // [0, 2560)
            const float4 v = wg[f];
            const int n    = f / 320;
            const int rem  = f - n * 320;
            const int c    = rem >> 5;
            const int rem2 = rem & 31;
            const int d    = rem2 >> 2;
            const int eqs  = rem2 & 3;
            unsigned* dst = (unsigned*)&wlds[((n * C_ + c) * 4 + (d >> 1)) * 4 + eqs]
                          + (d & 1) * 2;
            dst[0] = rne16(v.x) | (rne16(v.y) << 16);
            dst[1] = rne16(v.z) | (rne16(v.w) << 16);
        }
    }
    // ---- stage x -> LDS [n][b][XSTR_] fp32 ----
    {
        const float4* xg = (const float4*)x;
#pragma unroll
        for (int k = 0; k < 4; ++k) {
            const int g = k * 256 + tid;          // [0, 1024)
            const int b = g >> 4;
            const int r = g & 15;
            const int n = r >> 1;
            const int dq = r & 1;
            const float4 v = xg[((size_t)b * N_ + n0 + n) * 2 + dq];
            *(float4*)&xlds[(n * B_ + b) * XSTR_ + dq * 4] = v;
        }
    }
    __syncthreads();

    const int wv   = tid >> 6;
    const int lane = tid & 63;
    const int eq   = lane & 3;
    const int bl   = lane >> 2;
    const int h    = wv & 1;
    const int np   = wv >> 1;          // 0..1 (4 n each)
    const int b0   = h * 32 + bl;
    const int b1   = b0 + 16;

    unsigned vcp0[C_][2], vcp1[C_][2];
    if (!UNIFORM) {
#pragma unroll
        for (int c = 0; c < C_; ++c) {
            const float4 a = *(const float4*)(v_cum + (b0 * C_ + c) * E_ + eq * 4);
            vcp0[c][0] = pk2(a.x, a.y); vcp0[c][1] = pk2(a.z, a.w);
            const float4 d = *(const float4*)(v_cum + (b1 * C_ + c) * E_ + eq * 4);
            vcp1[c][0] = pk2(d.x, d.y); vcp1[c][1] = pk2(d.z, d.w);
        }
    }

    float4 acc0[C_], acc1[C_];
#pragma unroll
    for (int c = 0; c < C_; ++c) {
        acc0[c] = make_float4(0.f, 0.f, 0.f, 0.f);
        acc1[c] = make_float4(0.f, 0.f, 0.f, 0.f);
    }

#pragma unroll 1
    for (int j = 0; j < 4; ++j) {
        const int nl = np * 4 + j;
        const float4 xa0 = *(const float4*)&xlds[(nl * B_ + b0) * XSTR_];
        const float4 xa1 = *(const float4*)&xlds[(nl * B_ + b0) * XSTR_ + 4];
        const float4 xb0 = *(const float4*)&xlds[(nl * B_ + b1) * XSTR_];
        const float4 xb1 = *(const float4*)&xlds[(nl * B_ + b1) * XSTR_ + 4];
        const float xv0[D_] = {xa0.x, xa0.y, xa0.z, xa0.w, xa1.x, xa1.y, xa1.z, xa1.w};
        const float xv1[D_] = {xb0.x, xb0.y, xb0.z, xb0.w, xb1.x, xb1.y, xb1.z, xb1.w};
        const uint4* wn = &wlds[nl * (C_ * 16)];

        if (UNIFORM) {
#pragma unroll
            for (int c = 0; c < C_; ++c) {
#pragma unroll
                for (int d2 = 0; d2 < 4; ++d2) {
                    const uint4 q = wn[c * 16 + d2 * 4 + eq];
                    const float a0 = xv0[2 * d2], a1 = xv0[2 * d2 + 1];
                    const float c0 = xv1[2 * d2], c1 = xv1[2 * d2 + 1];
                    acc0[c].x = fmaf(a0, plo(q.x), fmaf(a1, plo(q.z), acc0[c].x));
                    acc0[c].y = fmaf(a0, phi(q.x), fmaf(a1, phi(q.z), acc0[c].y));
                    acc0[c].z = fmaf(a0, plo(q.y), fmaf(a1, plo(q.w), acc0[c].z));
                    acc0[c].w = fmaf(a0, phi(q.y), fmaf(a1, phi(q.w), acc0[c].w));
                    acc1[c].x = fmaf(c0, plo(q.x), fmaf(c1, plo(q.z), acc1[c].x));
                    acc1[c].y = fmaf(c0, phi(q.x), fmaf(c1, phi(q.z), acc1[c].y));
                    acc1[c].z = fmaf(c0, plo(q.y), fmaf(c1, plo(q.w), acc1[c].z));
                    acc1[c].w = fmaf(c0, phi(q.y), fmaf(c1, phi(q.w), acc1[c].w));
                }
            }
        } else {
            unsigned uhp0[C_][2], uhp1[C_][2];
            float wgt0[C_], wgt1[C_];
#pragma unroll
            for (int c = 0; c < C_; ++c) {
                float4 u0 = make_float4(0.f, 0.f, 0.f, 0.f);
                float4 u1 = make_float4(0.f, 0.f, 0.f, 0.f);
#pragma unroll
                for (int d2 = 0; d2 < 4; ++d2) {
                    const uint4 q = wn[c * 16 + d2 * 4 + eq];
                    const float a0 = xv0[2 * d2], a1 = xv0[2 * d2 + 1];
                    const float c0 = xv1[2 * d2], c1 = xv1[2 * d2 + 1];
                    u0.x = fmaf(a0, plo(q.x), fmaf(a1, plo(q.z), u0.x));
                    u0.y = fmaf(a0, phi(q.x), fmaf(a1, phi(q.z), u0.y));
                    u0.z = fmaf(a0, plo(q.y), fmaf(a1, plo(q.w), u0.z));
                    u0.w = fmaf(a0, phi(q.y), fmaf(a1, phi(q.w), u0.w));
                    u1.x = fmaf(c0, plo(q.x), fmaf(c1, plo(q.z), u1.x));
                    u1.y = fmaf(c0, phi(q.x), fmaf(c1, phi(q.z), u1.y));
                    u1.z = fmaf(c0, plo(q.y), fmaf(c1, plo(q.w), u1.z));
                    u1.w = fmaf(c0, phi(q.y), fmaf(c1, phi(q.w), u1.w));
                }
                float t0 = u0.x * plo(vcp0[c][0]);
                t0 = fmaf(u0.y, phi(vcp0[c][0]), t0);
                t0 = fmaf(u0.z, plo(vcp0[c][1]), t0);
                t0 = fmaf(u0.w, phi(vcp0[c][1]), t0);
                t0 += __shfl_xor(t0, 1); t0 += __shfl_xor(t0, 2);
                wgt0[c] = t0;
                float t1 = u1.x * plo(vcp1[c][0]);
                t1 = fmaf(u1.y, phi(vcp1[c][0]), t1);
                t1 = fmaf(u1.z, plo(vcp1[c][1]), t1);
                t1 = fmaf(u1.w, phi(vcp1[c][1]), t1);
                t1 += __shfl_xor(t1, 1); t1 += __shfl_xor(t1, 2);
                wgt1[c] = t1;
                uhp0[c][0] = pk2(u0.x, u0.y); uhp0[c][1] = pk2(u0.z, u0.w);
                uhp1[c][0] = pk2(u1.x, u1.y); uhp1[c][1] = pk2(u1.z, u1.w);
            }
            // softmax over C, no max-sub (logits bounded, exp safe in f32)
            float s0 = 0.f, s1 = 0.f;
#pragma unroll
            for (int c = 0; c < C_; ++c) {
                wgt0[c] = __expf(wgt0[c]); s0 += wgt0[c];
                wgt1[c] = __expf(wgt1[c]); s1 += wgt1[c];
            }
            const float i0 = 1.f / s0, i1 = 1.f / s1;
#pragma unroll
            for (int c = 0; c < C_; ++c) {
                const float g0 = wgt0[c] * i0, g1 = wgt1[c] * i1;
                acc0[c].x = fmaf(g0, plo(uhp0[c][0]), acc0[c].x);
                acc0[c].y = fmaf(g0, phi(uhp0[c][0]), acc0[c].y);
                acc0[c].z = fmaf(g0, plo(uhp0[c][1]), acc0[c].z);
                acc0[c].w = fmaf(g0, phi(uhp0[c][1]), acc0[c].w);
                acc1[c].x = fmaf(g1, plo(uhp1[c][0]), acc1[c].x);
                acc1[c].y = fmaf(g1, phi(uhp1[c][0]), acc1[c].y);
                acc1[c].z = fmaf(g1, plo(uhp1[c][1]), acc1[c].z);
                acc1[c].w = fmaf(g1, phi(uhp1[c][1]), acc1[c].w);
            }
        }
    }

    // ---- direct fp16 partial store: partial[b][slot][c*8 + eq*2] ----
    const float fold = UNIFORM ? 0.1f : 1.f;   // softmax(0) = 1/10 folded out
    const int slot = blk * 2 + np;
#pragma unroll
    for (int c = 0; c < C_; ++c) {
        *(uint2*)(partial + ((size_t)b0 * NSLOT_ + slot) * PROW_ + c * 8 + eq * 2) =
            make_uint2(hpack(acc0[c].x * fold, acc0[c].y * fold),
                       hpack(acc0[c].z * fold, acc0[c].w * fold));
        *(uint2*)(partial + ((size_t)b1 * NSLOT_ + slot) * PROW_ + c * 8 + eq * 2) =
            make_uint2(hpack(acc1[c].x * fold, acc1[c].y * fold),
                       hpack(acc1[c].z * fold, acc1[c].w * fold));
    }
}

// Block per b (512 thr, 8 slot-groups): sum partial[b][*][col] (coalesced
// 320B rows), squash, update v_cum/out. mode: 0 = set, 1 = add, 2 = out.
__global__ __launch_bounds__(512) void caps_reduce(
    const unsigned* __restrict__ partial, float* __restrict__ v_cum,
    float* __restrict__ out, int mode)
{
    const int b = (int)blockIdx.x;
    const int tid = (int)threadIdx.x;
    __shared__ float4 red[8][40];              // [gh][col] 5120 B
    const int gh  = tid >> 6;                  // 0..7
    const int col = tid & 63;                  // active < 40
    if (col < 40) {
        const unsigned* base =
            partial + ((size_t)b * NSLOT_ + (size_t)gh * (NSLOT_ / 8)) * PROW_ + col * 2;
        float s0 = 0.f, s1 = 0.f, s2 = 0.f, s3 = 0.f;
        for (int k = 0; k < NSLOT_ / 8; ++k) {
            const uint2 u = *(const uint2*)(base + (size_t)k * PROW_);
            const float2 f0 = hunpack(u.x);
            const float2 f1 = hunpack(u.y);
            s0 += f0.x; s1 += f0.y; s2 += f1.x; s3 += f1.y;
        }
        red[gh][col] = make_float4(s0, s1, s2, s3);
    }
    __syncthreads();
    if (tid < C_ * E_) {                       // ce = tid
        const int c4 = tid >> 2, e4 = tid & 3;
        float s = 0.f;
#pragma unroll
        for (int g = 0; g < 8; ++g) s += ((const float*)&red[g][c4])[e4];
        float p = s * s;                       // sum over e = tid&15 lanes
        p += __shfl_xor(p, 1); p += __shfl_xor(p, 2);
        p += __shfl_xor(p, 4); p += __shfl_xor(p, 8);
        const float sc = (p / (1.f + p)) * rsqrtf(p + EPS_);
        const float v = sc * s;
        const int o = b * (C_ * E_) + tid;
        if (mode == 2)      out[o] = v;
        else if (mode == 0) v_cum[o] = v;
        else                v_cum[o] += v;
    }
}

extern "C" void kernel_launch(void* const* d_in, const int* in_sizes, int n_in,
                              void* d_out, int out_size, void* d_ws, size_t ws_size,
                              hipStream_t stream) {
    const float* x = (const float*)d_in[0];
    const float* W = (const float*)d_in[1];
    float* out = (float*)d_out;

    unsigned* partial = (unsigned*)d_ws;   // 64*1024*80*4 = 20.97 MB
    float* v_cum = (float*)((char*)d_ws +
        (size_t)B_ * NSLOT_ * PROW_ * sizeof(unsigned));

    for (int t = 0; t < 3; ++t) {
        if (t == 0)
            caps_pass<true ><<<dim3(NBLK_), 256, 0, stream>>>(x, W, v_cum, partial);
        else
            caps_pass<false><<<dim3(NBLK_), 256, 0, stream>>>(x, W, v_cum, partial);
        caps_reduce<<<dim3(B_), 512, 0, stream>>>(partial, v_cum, out, t);
    }
}

// Round 13
// 99.581 us; speedup vs baseline: 3.4473x; 1.3772x over previous
//
#include <hip/hip_runtime.h>
#include <hip/hip_fp16.h>

#define B_ 64
#define N_ 4096
#define C_ 10
#define D_ 8
#define E_ 16
#define EPS_ 1e-7f
#define NT_ 4
#define NBLK_ (N_ / NT_)          // 1024 pass blocks
#define NSLOT_ NBLK_              // 1024 partial slots (1 per block)
#define XSTR_ 12                  // padded x row stride (f32)
#define PROW_ 80                  // u32 per partial row (160 halfs)

__device__ inline unsigned rne16(float f) {   // f32 -> bf16 round-nearest-even
    unsigned u = __float_as_uint(f);
    return (u + 0x7fffu + ((u >> 16) & 1u)) >> 16;
}
__device__ inline float plo(unsigned u) { return __uint_as_float(u << 16); }
__device__ inline float phi(unsigned u) { return __uint_as_float(u & 0xffff0000u); }
__device__ inline unsigned pk2(float a, float b) {   // bf16 trunc pack
    return (__float_as_uint(a) >> 16) | (__float_as_uint(b) & 0xffff0000u);
}
__device__ inline unsigned hpack(float a, float b) {
    __half2 t = __floats2half2_rn(a, b);
    return *(unsigned*)&t;
}
__device__ inline float2 hunpack(unsigned u) {
    return __half22float2(*(const __half2*)&u);
}

// Block: 256 thr = 4 waves = (h: b-half) x (cg: c-half, 5 classes each).
// All 4 waves process the SAME n together; thread owns TWO b (b0=h*32+bl,
// b1=b0+16) and FIVE c. Live set ~130 VGPR (vs 212 at full-c) -> 3 waves/SIMD.
// Softmax denominator: each cg computes its 5-class exp-sum, exchanges via a
// double-buffered LDS slot (one barrier per n). W bf16 granules: one
// ds_read_b128 = 2d x 4e = 16 FMAs per b, shared across both b.
template <bool UNIFORM>
__global__ __launch_bounds__(256, 3) void caps_pass(
    const float* __restrict__ x, const float* __restrict__ W,
    const float* __restrict__ v_cum, unsigned* __restrict__ partial)
{
    __shared__ uint4 wlds[NT_ * C_ * 16];       // 640 uint4 = 10240 B
    __shared__ float xlds[NT_ * B_ * XSTR_];    // 12288 B
    __shared__ float xch[2][2][2][16][2];       // [buf][cg][h][bl][b01] 1024 B

    const int tid = (int)threadIdx.x;
    const int blk = (int)blockIdx.x;
    const int n0  = blk * NT_;

    // ---- stage W -> LDS bf16 swizzled [n][c][d2][eq]{d&1 dword-pair} ----
    {
        const float4* wg = (const float4*)W + (size_t)blk * (NT_ * 320);
#pragma unroll
        for (int k = 0; k < 5; ++k) {
            const int f = k * 256 + tid;          // [0, 1280)
            const float4 v = wg[f];
            const int n    = f / 320;
            const int rem  = f - n * 320;
            const int c    = rem >> 5;
            const int rem2 = rem & 31;
            const int d    = rem2 >> 2;
            const int eqs  = rem2 & 3;
            unsigned* dst = (unsigned*)&wlds[((n * C_ + c) * 4 + (d >> 1)) * 4 + eqs]
                          + (d & 1) * 2;
            dst[0] = rne16(v.x) | (rne16(v.y) << 16);
            dst[1] = rne16(v.z) | (rne16(v.w) << 16);
        }
    }
    // ---- stage x -> LDS [n][b][XSTR_] fp32 ----
    {
        const float4* xg = (const float4*)x;
#pragma unroll
        for (int k = 0; k < 2; ++k) {
            const int g = k * 256 + tid;          // [0, 512)
            const int b = g >> 3;
            const int r = g & 7;
            const int n = r >> 1;
            const int dq = r & 1;
            const float4 v = xg[((size_t)b * N_ + n0 + n) * 2 + dq];
            *(float4*)&xlds[(n * B_ + b) * XSTR_ + dq * 4] = v;
        }
    }
    __syncthreads();

    const int wv   = tid >> 6;
    const int lane = tid & 63;
    const int eq   = lane & 3;
    const int bl   = lane >> 2;
    const int h    = wv & 1;
    const int cg   = wv >> 1;          // c-group: 0 -> c 0..4, 1 -> c 5..9
    const int b0   = h * 32 + bl;
    const int b1   = b0 + 16;
    const int cbase = cg * 5;

    unsigned vcp0[5][2], vcp1[5][2];
    if (!UNIFORM) {
#pragma unroll
        for (int cc = 0; cc < 5; ++cc) {
            const int c = cbase + cc;
            const float4 a = *(const float4*)(v_cum + (b0 * C_ + c) * E_ + eq * 4);
            vcp0[cc][0] = pk2(a.x, a.y); vcp0[cc][1] = pk2(a.z, a.w);
            const float4 d = *(const float4*)(v_cum + (b1 * C_ + c) * E_ + eq * 4);
            vcp1[cc][0] = pk2(d.x, d.y); vcp1[cc][1] = pk2(d.z, d.w);
        }
    }

    float4 acc0[5], acc1[5];
#pragma unroll
    for (int cc = 0; cc < 5; ++cc) {
        acc0[cc] = make_float4(0.f, 0.f, 0.f, 0.f);
        acc1[cc] = make_float4(0.f, 0.f, 0.f, 0.f);
    }

#pragma unroll 1
    for (int j = 0; j < NT_; ++j) {
        const float4 xa0 = *(const float4*)&xlds[(j * B_ + b0) * XSTR_];
        const float4 xa1 = *(const float4*)&xlds[(j * B_ + b0) * XSTR_ + 4];
        const float4 xb0 = *(const float4*)&xlds[(j * B_ + b1) * XSTR_];
        const float4 xb1 = *(const float4*)&xlds[(j * B_ + b1) * XSTR_ + 4];
        const float xv0[D_] = {xa0.x, xa0.y, xa0.z, xa0.w, xa1.x, xa1.y, xa1.z, xa1.w};
        const float xv1[D_] = {xb0.x, xb0.y, xb0.z, xb0.w, xb1.x, xb1.y, xb1.z, xb1.w};
        const uint4* wn = &wlds[j * (C_ * 16) + cbase * 16];

        if (UNIFORM) {
#pragma unroll
            for (int cc = 0; cc < 5; ++cc) {
#pragma unroll
                for (int d2 = 0; d2 < 4; ++d2) {
                    const uint4 q = wn[cc * 16 + d2 * 4 + eq];
                    const float a0 = xv0[2 * d2], a1 = xv0[2 * d2 + 1];
                    const float c0 = xv1[2 * d2], c1 = xv1[2 * d2 + 1];
                    acc0[cc].x = fmaf(a0, plo(q.x), fmaf(a1, plo(q.z), acc0[cc].x));
                    acc0[cc].y = fmaf(a0, phi(q.x), fmaf(a1, phi(q.z), acc0[cc].y));
                    acc0[cc].z = fmaf(a0, plo(q.y), fmaf(a1, plo(q.w), acc0[cc].z));
                    acc0[cc].w = fmaf(a0, phi(q.y), fmaf(a1, phi(q.w), acc0[cc].w));
                    acc1[cc].x = fmaf(c0, plo(q.x), fmaf(c1, plo(q.z), acc1[cc].x));
                    acc1[cc].y = fmaf(c0, phi(q.x), fmaf(c1, phi(q.z), acc1[cc].y));
                    acc1[cc].z = fmaf(c0, plo(q.y), fmaf(c1, plo(q.w), acc1[cc].z));
                    acc1[cc].w = fmaf(c0, phi(q.y), fmaf(c1, phi(q.w), acc1[cc].w));
                }
            }
        } else {
            unsigned uhp0[5][2], uhp1[5][2];
            float wgt0[5], wgt1[5];
            float s0 = 0.f, s1 = 0.f;
#pragma unroll
            for (int cc = 0; cc < 5; ++cc) {
                float4 u0 = make_float4(0.f, 0.f, 0.f, 0.f);
                float4 u1 = make_float4(0.f, 0.f, 0.f, 0.f);
#pragma unroll
                for (int d2 = 0; d2 < 4; ++d2) {
                    const uint4 q = wn[cc * 16 + d2 * 4 + eq];
                    const float a0 = xv0[2 * d2], a1 = xv0[2 * d2 + 1];
                    const float c0 = xv1[2 * d2], c1 = xv1[2 * d2 + 1];
                    u0.x = fmaf(a0, plo(q.x), fmaf(a1, plo(q.z), u0.x));
                    u0.y = fmaf(a0, phi(q.x), fmaf(a1, phi(q.z), u0.y));
                    u0.z = fmaf(a0, plo(q.y), fmaf(a1, plo(q.w), u0.z));
                    u0.w = fmaf(a0, phi(q.y), fmaf(a1, phi(q.w), u0.w));
                    u1.x = fmaf(c0, plo(q.x), fmaf(c1, plo(q.z), u1.x));
                    u1.y = fmaf(c0, phi(q.x), fmaf(c1, phi(q.z), u1.y));
                    u1.z = fmaf(c0, plo(q.y), fmaf(c1, plo(q.w), u1.z));
                    u1.w = fmaf(c0, phi(q.y), fmaf(c1, phi(q.w), u1.w));
                }
                float t0 = u0.x * plo(vcp0[cc][0]);
                t0 = fmaf(u0.y, phi(vcp0[cc][0]), t0);
                t0 = fmaf(u0.z, plo(vcp0[cc][1]), t0);
                t0 = fmaf(u0.w, phi(vcp0[cc][1]), t0);
                t0 += __shfl_xor(t0, 1); t0 += __shfl_xor(t0, 2);
                float t1 = u1.x * plo(vcp1[cc][0]);
                t1 = fmaf(u1.y, phi(vcp1[cc][0]), t1);
                t1 = fmaf(u1.z, plo(vcp1[cc][1]), t1);
                t1 = fmaf(u1.w, phi(vcp1[cc][1]), t1);
                t1 += __shfl_xor(t1, 1); t1 += __shfl_xor(t1, 2);
                wgt0[cc] = __expf(t0); s0 += wgt0[cc];
                wgt1[cc] = __expf(t1); s1 += wgt1[cc];
                uhp0[cc][0] = pk2(u0.x, u0.y); uhp0[cc][1] = pk2(u0.z, u0.w);
                uhp1[cc][0] = pk2(u1.x, u1.y); uhp1[cc][1] = pk2(u1.z, u1.w);
            }
            // exchange the 5-class exp-sums with the other c-group
            if (eq == 0) {
                xch[j & 1][cg][h][bl][0] = s0;
                xch[j & 1][cg][h][bl][1] = s1;
            }
            __syncthreads();
            const float i0 = 1.f / (s0 + xch[j & 1][cg ^ 1][h][bl][0]);
            const float i1 = 1.f / (s1 + xch[j & 1][cg ^ 1][h][bl][1]);
#pragma unroll
            for (int cc = 0; cc < 5; ++cc) {
                const float g0 = wgt0[cc] * i0, g1 = wgt1[cc] * i1;
                acc0[cc].x = fmaf(g0, plo(uhp0[cc][0]), acc0[cc].x);
                acc0[cc].y = fmaf(g0, phi(uhp0[cc][0]), acc0[cc].y);
                acc0[cc].z = fmaf(g0, plo(uhp0[cc][1]), acc0[cc].z);
                acc0[cc].w = fmaf(g0, phi(uhp0[cc][1]), acc0[cc].w);
                acc1[cc].x = fmaf(g1, plo(uhp1[cc][0]), acc1[cc].x);
                acc1[cc].y = fmaf(g1, phi(uhp1[cc][0]), acc1[cc].y);
                acc1[cc].z = fmaf(g1, plo(uhp1[cc][1]), acc1[cc].z);
                acc1[cc].w = fmaf(g1, phi(uhp1[cc][1]), acc1[cc].w);
            }
        }
    }

    // ---- direct fp16 partial store: partial[b][slot][c*8 + eq*2] ----
    const float fold = UNIFORM ? 0.1f : 1.f;   // softmax(0) = 1/10 folded out
#pragma unroll
    for (int cc = 0; cc < 5; ++cc) {
        const int c = cbase + cc;
        *(uint2*)(partial + ((size_t)b0 * NSLOT_ + blk) * PROW_ + c * 8 + eq * 2) =
            make_uint2(hpack(acc0[cc].x * fold, acc0[cc].y * fold),
                       hpack(acc0[cc].z * fold, acc0[cc].w * fold));
        *(uint2*)(partial + ((size_t)b1 * NSLOT_ + blk) * PROW_ + c * 8 + eq * 2) =
            make_uint2(hpack(acc1[cc].x * fold, acc1[cc].y * fold),
                       hpack(acc1[cc].z * fold, acc1[cc].w * fold));
    }
}

// Block per b (512 thr, 8 slot-groups): sum partial[b][*][col] (coalesced
// 320B rows), squash, update v_cum/out. mode: 0 = set, 1 = add, 2 = out.
__global__ __launch_bounds__(512) void caps_reduce(
    const unsigned* __restrict__ partial, float* __restrict__ v_cum,
    float* __restrict__ out, int mode)
{
    const int b = (int)blockIdx.x;
    const int tid = (int)threadIdx.x;
    __shared__ float4 red[8][40];              // [gh][col] 5120 B
    const int gh  = tid >> 6;                  // 0..7
    const int col = tid & 63;                  // active < 40
    if (col < 40) {
        const unsigned* base =
            partial + ((size_t)b * NSLOT_ + (size_t)gh * (NSLOT_ / 8)) * PROW_ + col * 2;
        float s0 = 0.f, s1 = 0.f, s2 = 0.f, s3 = 0.f;
        for (int k = 0; k < NSLOT_ / 8; ++k) {
            const uint2 u = *(const uint2*)(base + (size_t)k * PROW_);
            const float2 f0 = hunpack(u.x);
            const float2 f1 = hunpack(u.y);
            s0 += f0.x; s1 += f0.y; s2 += f1.x; s3 += f1.y;
        }
        red[gh][col] = make_float4(s0, s1, s2, s3);
    }
    __syncthreads();
    if (tid < C_ * E_) {                       // ce = tid
        const int c4 = tid >> 2, e4 = tid & 3;
        float s = 0.f;
#pragma unroll
        for (int g = 0; g < 8; ++g) s += ((const float*)&red[g][c4])[e4];
        float p = s * s;                       // sum over e = tid&15 lanes
        p += __shfl_xor(p, 1); p += __shfl_xor(p, 2);
        p += __shfl_xor(p, 4); p += __shfl_xor(p, 8);
        const float sc = (p / (1.f + p)) * rsqrtf(p + EPS_);
        const float v = sc * s;
        const int o = b * (C_ * E_) + tid;
        if (mode == 2)      out[o] = v;
        else if (mode == 0) v_cum[o] = v;
        else                v_cum[o] += v;
    }
}

extern "C" void kernel_launch(void* const* d_in, const int* in_sizes, int n_in,
                              void* d_out, int out_size, void* d_ws, size_t ws_size,
                              hipStream_t stream) {
    const float* x = (const float*)d_in[0];
    const float* W = (const float*)d_in[1];
    float* out = (float*)d_out;

    unsigned* partial = (unsigned*)d_ws;   // 64*1024*80*4 = 20.97 MB
    float* v_cum = (float*)((char*)d_ws +
        (size_t)B_ * NSLOT_ * PROW_ * sizeof(unsigned));

    for (int t = 0; t < 3; ++t) {
        if (t == 0)
            caps_pass<true ><<<dim3(NBLK_), 256, 0, stream>>>(x, W, v_cum, partial);
        else
            caps_pass<false><<<dim3(NBLK_), 256, 0, stream>>>(x, W, v_cum, partial);
        caps_reduce<<<dim3(B_), 512, 0, stream>>>(partial, v_cum, out, t);
    }
}

// Round 15
// 90.614 us; speedup vs baseline: 3.7884x; 1.0990x over previous
//
#include <hip/hip_runtime.h>
#include <hip/hip_fp16.h>

#define B_ 64
#define N_ 4096
#define C_ 10
#define D_ 8
#define E_ 16
#define EPS_ 1e-7f
#define NT_ 4
#define NBLK_ (N_ / NT_)          // 1024 pass blocks
#define NSLOT_ NBLK_              // 1024 partial slots (1 per block)
#define PROW_ 80                  // u32 per partial row (160 halfs)

typedef _Float16 h2_t __attribute__((ext_vector_type(2)));
typedef __fp16   p2_t __attribute__((ext_vector_type(2)));   // cvt_pkrtz ret type

__device__ inline unsigned pkh(float a, float b) {   // f32x2 -> packed fp16
    p2_t t = __builtin_amdgcn_cvt_pkrtz(a, b);
    return *(unsigned*)&t;
}
#if __has_builtin(__builtin_amdgcn_fdot2)
__device__ inline float fd2(unsigned a, unsigned b, float c) {
    h2_t av = *(h2_t*)&a, bv = *(h2_t*)&b;
    return __builtin_amdgcn_fdot2(av, bv, c, false);
}
#else
__device__ inline float fd2(unsigned a, unsigned b, float c) {
    h2_t av = *(h2_t*)&a, bv = *(h2_t*)&b;
    return fmaf((float)av.x, (float)bv.x, fmaf((float)av.y, (float)bv.y, c));
}
#endif
__device__ inline float hlo(unsigned u) { h2_t t = *(h2_t*)&u; return (float)t.x; }
__device__ inline float hhi(unsigned u) { h2_t t = *(h2_t*)&u; return (float)t.y; }
__device__ inline unsigned hpack(float a, float b) {
    __half2 t = __floats2half2_rn(a, b);
    return *(unsigned*)&t;
}
__device__ inline float2 hunpack(unsigned u) {
    return __half22float2(*(const __half2*)&u);
}

// Block: 256 thr = 4 waves = (h: b-half) x (cg: c-half, 5 classes each).
// Thread owns TWO b (b0=h*32+bl, b1=b0+16) and FIVE c. All data fp16-packed
// along d-pairs; contraction via v_dot2_f32_f16 (2 MACs/instr, no unpack).
// W granule uint4 = 4 e-words, word = (W[2d2,e], W[2d2+1,e]); x word =
// (x[2d2], x[2d2+1]). Softmax denom exchanged between c-halves via LDS.
template <bool UNIFORM>
__global__ __launch_bounds__(256, 3) void caps_pass(
    const float* __restrict__ x, const float* __restrict__ W,
    const float* __restrict__ v_cum, unsigned* __restrict__ partial)
{
    __shared__ uint4    wlds[NT_ * C_ * 16];    // 640 uint4 = 10240 B
    __shared__ unsigned xlds[NT_ * B_ * 4];     // 4096 B
    __shared__ float    xch[2][2][2][16][2];    // 1024 B

    const int tid = (int)threadIdx.x;
    const int blk = (int)blockIdx.x;
    const int n0  = blk * NT_;

    // ---- stage W -> LDS fp16 d-pair granules [n][c][d2][eq] ----
    {
        const float4* wg = (const float4*)W + (size_t)blk * (NT_ * 320);
#pragma unroll
        for (int k = 0; k < 3; ++k) {
            const int g = k * 256 + tid;          // [0, 640)
            if (g < NT_ * C_ * 16) {
                const int n   = g / 160;
                const int rem = g - n * 160;
                const int c   = rem >> 4;
                const int r2  = rem & 15;
                const int d2  = r2 >> 2;
                const int eqs = r2 & 3;
                const float4 g0 = wg[n * 320 + c * 32 + (2 * d2) * 4 + eqs];
                const float4 g1 = wg[n * 320 + c * 32 + (2 * d2 + 1) * 4 + eqs];
                wlds[((n * C_ + c) * 4 + d2) * 4 + eqs] =
                    make_uint4(pkh(g0.x, g1.x), pkh(g0.y, g1.y),
                               pkh(g0.z, g1.z), pkh(g0.w, g1.w));
            }
        }
    }
    // ---- stage x -> LDS fp16 d-pair words [n][b][4] ----
    {
        const float4* xg = (const float4*)x;
#pragma unroll
        for (int k = 0; k < 2; ++k) {
            const int g = k * 256 + tid;          // [0, 512)
            const int b = g >> 3;
            const int r = g & 7;
            const int n = r >> 1;
            const int dq = r & 1;
            const float4 v = xg[((size_t)b * N_ + n0 + n) * 2 + dq];
            *(uint2*)&xlds[(n * B_ + b) * 4 + dq * 2] =
                make_uint2(pkh(v.x, v.y), pkh(v.z, v.w));
        }
    }
    __syncthreads();

    const int wv   = tid >> 6;
    const int lane = tid & 63;
    const int eq   = lane & 3;
    const int bl   = lane >> 2;
    const int h    = wv & 1;
    const int cg   = wv >> 1;          // c-group: 0 -> c 0..4, 1 -> c 5..9
    const int b0   = h * 32 + bl;
    const int b1   = b0 + 16;
    const int cbase = cg * 5;

    unsigned vcp0[5][2], vcp1[5][2];
    if (!UNIFORM) {
#pragma unroll
        for (int cc = 0; cc < 5; ++cc) {
            const int c = cbase + cc;
            const float4 a = *(const float4*)(v_cum + (b0 * C_ + c) * E_ + eq * 4);
            vcp0[cc][0] = pkh(a.x, a.y); vcp0[cc][1] = pkh(a.z, a.w);
            const float4 d = *(const float4*)(v_cum + (b1 * C_ + c) * E_ + eq * 4);
            vcp1[cc][0] = pkh(d.x, d.y); vcp1[cc][1] = pkh(d.z, d.w);
        }
    }

    float4 acc0[5], acc1[5];
#pragma unroll
    for (int cc = 0; cc < 5; ++cc) {
        acc0[cc] = make_float4(0.f, 0.f, 0.f, 0.f);
        acc1[cc] = make_float4(0.f, 0.f, 0.f, 0.f);
    }

#pragma unroll 1
    for (int j = 0; j < NT_; ++j) {
        const uint4 xq0 = *(const uint4*)&xlds[(j * B_ + b0) * 4];
        const uint4 xq1 = *(const uint4*)&xlds[(j * B_ + b1) * 4];
        const unsigned xa[4] = {xq0.x, xq0.y, xq0.z, xq0.w};
        const unsigned xb[4] = {xq1.x, xq1.y, xq1.z, xq1.w};

        if (UNIFORM) {
#pragma unroll
            for (int cc = 0; cc < 5; ++cc) {
                const uint4* wq = &wlds[(j * C_ + cbase + cc) * 16];
#pragma unroll
                for (int d2 = 0; d2 < 4; ++d2) {
                    const uint4 q = wq[d2 * 4 + eq];
                    acc0[cc].x = fd2(xa[d2], q.x, acc0[cc].x);
                    acc0[cc].y = fd2(xa[d2], q.y, acc0[cc].y);
                    acc0[cc].z = fd2(xa[d2], q.z, acc0[cc].z);
                    acc0[cc].w = fd2(xa[d2], q.w, acc0[cc].w);
                    acc1[cc].x = fd2(xb[d2], q.x, acc1[cc].x);
                    acc1[cc].y = fd2(xb[d2], q.y, acc1[cc].y);
                    acc1[cc].z = fd2(xb[d2], q.z, acc1[cc].z);
                    acc1[cc].w = fd2(xb[d2], q.w, acc1[cc].w);
                }
            }
        } else {
            unsigned uhp0[5][2], uhp1[5][2];
            float wgt0[5], wgt1[5];
            float s0 = 0.f, s1 = 0.f;
#pragma unroll
            for (int cc = 0; cc < 5; ++cc) {
                const uint4* wq = &wlds[(j * C_ + cbase + cc) * 16];
                float4 u0 = make_float4(0.f, 0.f, 0.f, 0.f);
                float4 u1 = make_float4(0.f, 0.f, 0.f, 0.f);
#pragma unroll
                for (int d2 = 0; d2 < 4; ++d2) {
                    const uint4 q = wq[d2 * 4 + eq];
                    u0.x = fd2(xa[d2], q.x, u0.x);
                    u0.y = fd2(xa[d2], q.y, u0.y);
                    u0.z = fd2(xa[d2], q.z, u0.z);
                    u0.w = fd2(xa[d2], q.w, u0.w);
                    u1.x = fd2(xb[d2], q.x, u1.x);
                    u1.y = fd2(xb[d2], q.y, u1.y);
                    u1.z = fd2(xb[d2], q.z, u1.z);
                    u1.w = fd2(xb[d2], q.w, u1.w);
                }
                const unsigned up00 = pkh(u0.x, u0.y), up01 = pkh(u0.z, u0.w);
                const unsigned up10 = pkh(u1.x, u1.y), up11 = pkh(u1.z, u1.w);
                float t0 = fd2(up00, vcp0[cc][0], fd2(up01, vcp0[cc][1], 0.f));
                t0 += __shfl_xor(t0, 1); t0 += __shfl_xor(t0, 2);
                float t1 = fd2(up10, vcp1[cc][0], fd2(up11, vcp1[cc][1], 0.f));
                t1 += __shfl_xor(t1, 1); t1 += __shfl_xor(t1, 2);
                wgt0[cc] = __expf(t0); s0 += wgt0[cc];
                wgt1[cc] = __expf(t1); s1 += wgt1[cc];
                uhp0[cc][0] = up00; uhp0[cc][1] = up01;
                uhp1[cc][0] = up10; uhp1[cc][1] = up11;
            }
            // exchange the 5-class exp-sums with the other c-group
            if (eq == 0) {
                xch[j & 1][cg][h][bl][0] = s0;
                xch[j & 1][cg][h][bl][1] = s1;
            }
            __syncthreads();
            const float i0 = 1.f / (s0 + xch[j & 1][cg ^ 1][h][bl][0]);
            const float i1 = 1.f / (s1 + xch[j & 1][cg ^ 1][h][bl][1]);
#pragma unroll
            for (int cc = 0; cc < 5; ++cc) {
                const float g0 = wgt0[cc] * i0, g1 = wgt1[cc] * i1;
                acc0[cc].x = fmaf(g0, hlo(uhp0[cc][0]), acc0[cc].x);
                acc0[cc].y = fmaf(g0, hhi(uhp0[cc][0]), acc0[cc].y);
                acc0[cc].z = fmaf(g0, hlo(uhp0[cc][1]), acc0[cc].z);
                acc0[cc].w = fmaf(g0, hhi(uhp0[cc][1]), acc0[cc].w);
                acc1[cc].x = fmaf(g1, hlo(uhp1[cc][0]), acc1[cc].x);
                acc1[cc].y = fmaf(g1, hhi(uhp1[cc][0]), acc1[cc].y);
                acc1[cc].z = fmaf(g1, hlo(uhp1[cc][1]), acc1[cc].z);
                acc1[cc].w = fmaf(g1, hhi(uhp1[cc][1]), acc1[cc].w);
            }
        }
    }

    // ---- direct fp16 partial store: partial[b][slot][c*8 + eq*2] ----
    const float fold = UNIFORM ? 0.1f : 1.f;   // softmax(0) = 1/10 folded out
#pragma unroll
    for (int cc = 0; cc < 5; ++cc) {
        const int c = cbase + cc;
        *(uint2*)(partial + ((size_t)b0 * NSLOT_ + blk) * PROW_ + c * 8 + eq * 2) =
            make_uint2(hpack(acc0[cc].x * fold, acc0[cc].y * fold),
                       hpack(acc0[cc].z * fold, acc0[cc].w * fold));
        *(uint2*)(partial + ((size_t)b1 * NSLOT_ + blk) * PROW_ + c * 8 + eq * 2) =
            make_uint2(hpack(acc1[cc].x * fold, acc1[cc].y * fold),
                       hpack(acc1[cc].z * fold, acc1[cc].w * fold));
    }
}

// Block per b (512 thr, 8 slot-groups): sum partial[b][*][col] (coalesced
// 320B rows), squash, update v_cum/out. mode: 0 = set, 1 = add, 2 = out.
__global__ __launch_bounds__(512) void caps_reduce(
    const unsigned* __restrict__ partial, float* __restrict__ v_cum,
    float* __restrict__ out, int mode)
{
    const int b = (int)blockIdx.x;
    const int tid = (int)threadIdx.x;
    __shared__ float4 red[8][40];              // [gh][col] 5120 B
    const int gh  = tid >> 6;                  // 0..7
    const int col = tid & 63;                  // active < 40
    if (col < 40) {
        const unsigned* base =
            partial + ((size_t)b * NSLOT_ + (size_t)gh * (NSLOT_ / 8)) * PROW_ + col * 2;
        float s0 = 0.f, s1 = 0.f, s2 = 0.f, s3 = 0.f;
        for (int k = 0; k < NSLOT_ / 8; ++k) {
            const uint2 u = *(const uint2*)(base + (size_t)k * PROW_);
            const float2 f0 = hunpack(u.x);
            const float2 f1 = hunpack(u.y);
            s0 += f0.x; s1 += f0.y; s2 += f1.x; s3 += f1.y;
        }
        red[gh][col] = make_float4(s0, s1, s2, s3);
    }
    __syncthreads();
    if (tid < C_ * E_) {                       // ce = tid
        const int c4 = tid >> 2, e4 = tid & 3;
        float s = 0.f;
#pragma unroll
        for (int g = 0; g < 8; ++g) s += ((const float*)&red[g][c4])[e4];
        float p = s * s;                       // sum over e = tid&15 lanes
        p += __shfl_xor(p, 1); p += __shfl_xor(p, 2);
        p += __shfl_xor(p, 4); p += __shfl_xor(p, 8);
        const float sc = (p / (1.f + p)) * rsqrtf(p + EPS_);
        const float v = sc * s;
        const int o = b * (C_ * E_) + tid;
        if (mode == 2)      out[o] = v;
        else if (mode == 0) v_cum[o] = v;
        else                v_cum[o] += v;
    }
}

extern "C" void kernel_launch(void* const* d_in, const int* in_sizes, int n_in,
                              void* d_out, int out_size, void* d_ws, size_t ws_size,
                              hipStream_t stream) {
    const float* x = (const float*)d_in[0];
    const float* W = (const float*)d_in[1];
    float* out = (float*)d_out;

    unsigned* partial = (unsigned*)d_ws;   // 64*1024*80*4 = 20.97 MB
    float* v_cum = (float*)((char*)d_ws +
        (size_t)B_ * NSLOT_ * PROW_ * sizeof(unsigned));

    for (int t = 0; t < 3; ++t) {
        if (t == 0)
            caps_pass<true ><<<dim3(NBLK_), 256, 0, stream>>>(x, W, v_cum, partial);
        else
            caps_pass<false><<<dim3(NBLK_), 256, 0, stream>>>(x, W, v_cum, partial);
        caps_reduce<<<dim3(B_), 512, 0, stream>>>(partial, v_cum, out, t);
    }
}

// Round 16
// 83.772 us; speedup vs baseline: 4.0979x; 1.0817x over previous
//
#include <hip/hip_runtime.h>
#include <hip/hip_fp16.h>

#define B_ 64
#define N_ 4096
#define C_ 10
#define D_ 8
#define E_ 16
#define EPS_ 1e-7f
#define NT_ 4
#define NBLK_ (N_ / NT_)          // 1024 pass blocks
#define NSLOT_ NBLK_              // 1024 partial slots (1 per block)
#define PROW_ 80                  // u32 per partial row (160 halfs)
#define NSG_ 8                    // reduce stage-A slot groups

typedef _Float16 h2_t __attribute__((ext_vector_type(2)));
typedef __fp16   p2_t __attribute__((ext_vector_type(2)));   // cvt_pkrtz ret type

__device__ inline unsigned pkh(float a, float b) {   // f32x2 -> packed fp16
    p2_t t = __builtin_amdgcn_cvt_pkrtz(a, b);
    return *(unsigned*)&t;
}
#if __has_builtin(__builtin_amdgcn_fdot2)
__device__ inline float fd2(unsigned a, unsigned b, float c) {
    h2_t av = *(h2_t*)&a, bv = *(h2_t*)&b;
    return __builtin_amdgcn_fdot2(av, bv, c, false);
}
#else
__device__ inline float fd2(unsigned a, unsigned b, float c) {
    h2_t av = *(h2_t*)&a, bv = *(h2_t*)&b;
    return fmaf((float)av.x, (float)bv.x, fmaf((float)av.y, (float)bv.y, c));
}
#endif
__device__ inline float hlo(unsigned u) { h2_t t = *(h2_t*)&u; return (float)t.x; }
__device__ inline float hhi(unsigned u) { h2_t t = *(h2_t*)&u; return (float)t.y; }
__device__ inline unsigned hpack(float a, float b) {
    __half2 t = __floats2half2_rn(a, b);
    return *(unsigned*)&t;
}
__device__ inline float2 hunpack(unsigned u) {
    return __half22float2(*(const __half2*)&u);
}

// Block: 256 thr = 4 waves = (h: b-half) x (cg: c-half, 5 classes each).
// Thread owns TWO b (b0=h*32+bl, b1=b0+16) and FIVE c; fp16 d-pair data,
// v_dot2_f32_f16 contraction. launch_bounds(256,4): live set ~115 VGPR fits
// the 128 cap -> 4 waves/SIMD (spill tripwire: WRITE_SIZE >> 22 MB/pass).
template <bool UNIFORM>
__global__ __launch_bounds__(256, 4) void caps_pass(
    const float* __restrict__ x, const float* __restrict__ W,
    const float* __restrict__ v_cum, unsigned* __restrict__ partial)
{
    __shared__ uint4    wlds[NT_ * C_ * 16];    // 640 uint4 = 10240 B
    __shared__ unsigned xlds[NT_ * B_ * 4];     // 4096 B
    __shared__ float    xch[2][2][2][16][2];    // 1024 B

    const int tid = (int)threadIdx.x;
    const int blk = (int)blockIdx.x;
    const int n0  = blk * NT_;

    // ---- stage W -> LDS fp16 d-pair granules [n][c][d2][eq] ----
    {
        const float4* wg = (const float4*)W + (size_t)blk * (NT_ * 320);
#pragma unroll
        for (int k = 0; k < 3; ++k) {
            const int g = k * 256 + tid;          // [0, 640)
            if (g < NT_ * C_ * 16) {
                const int n   = g / 160;
                const int rem = g - n * 160;
                const int c   = rem >> 4;
                const int r2  = rem & 15;
                const int d2  = r2 >> 2;
                const int eqs = r2 & 3;
                const float4 g0 = wg[n * 320 + c * 32 + (2 * d2) * 4 + eqs];
                const float4 g1 = wg[n * 320 + c * 32 + (2 * d2 + 1) * 4 + eqs];
                wlds[((n * C_ + c) * 4 + d2) * 4 + eqs] =
                    make_uint4(pkh(g0.x, g1.x), pkh(g0.y, g1.y),
                               pkh(g0.z, g1.z), pkh(g0.w, g1.w));
            }
        }
    }
    // ---- stage x -> LDS fp16 d-pair words [n][b][4] ----
    {
        const float4* xg = (const float4*)x;
#pragma unroll
        for (int k = 0; k < 2; ++k) {
            const int g = k * 256 + tid;          // [0, 512)
            const int b = g >> 3;
            const int r = g & 7;
            const int n = r >> 1;
            const int dq = r & 1;
            const float4 v = xg[((size_t)b * N_ + n0 + n) * 2 + dq];
            *(uint2*)&xlds[(n * B_ + b) * 4 + dq * 2] =
                make_uint2(pkh(v.x, v.y), pkh(v.z, v.w));
        }
    }
    __syncthreads();

    const int wv   = tid >> 6;
    const int lane = tid & 63;
    const int eq   = lane & 3;
    const int bl   = lane >> 2;
    const int h    = wv & 1;
    const int cg   = wv >> 1;          // c-group: 0 -> c 0..4, 1 -> c 5..9
    const int b0   = h * 32 + bl;
    const int b1   = b0 + 16;
    const int cbase = cg * 5;

    unsigned vcp0[5][2], vcp1[5][2];
    if (!UNIFORM) {
#pragma unroll
        for (int cc = 0; cc < 5; ++cc) {
            const int c = cbase + cc;
            const float4 a = *(const float4*)(v_cum + (b0 * C_ + c) * E_ + eq * 4);
            vcp0[cc][0] = pkh(a.x, a.y); vcp0[cc][1] = pkh(a.z, a.w);
            const float4 d = *(const float4*)(v_cum + (b1 * C_ + c) * E_ + eq * 4);
            vcp1[cc][0] = pkh(d.x, d.y); vcp1[cc][1] = pkh(d.z, d.w);
        }
    }

    float4 acc0[5], acc1[5];
#pragma unroll
    for (int cc = 0; cc < 5; ++cc) {
        acc0[cc] = make_float4(0.f, 0.f, 0.f, 0.f);
        acc1[cc] = make_float4(0.f, 0.f, 0.f, 0.f);
    }

#pragma unroll 1
    for (int j = 0; j < NT_; ++j) {
        const uint4 xq0 = *(const uint4*)&xlds[(j * B_ + b0) * 4];
        const uint4 xq1 = *(const uint4*)&xlds[(j * B_ + b1) * 4];
        const unsigned xa[4] = {xq0.x, xq0.y, xq0.z, xq0.w};
        const unsigned xb[4] = {xq1.x, xq1.y, xq1.z, xq1.w};

        if (UNIFORM) {
#pragma unroll
            for (int cc = 0; cc < 5; ++cc) {
                const uint4* wq = &wlds[(j * C_ + cbase + cc) * 16];
#pragma unroll
                for (int d2 = 0; d2 < 4; ++d2) {
                    const uint4 q = wq[d2 * 4 + eq];
                    acc0[cc].x = fd2(xa[d2], q.x, acc0[cc].x);
                    acc0[cc].y = fd2(xa[d2], q.y, acc0[cc].y);
                    acc0[cc].z = fd2(xa[d2], q.z, acc0[cc].z);
                    acc0[cc].w = fd2(xa[d2], q.w, acc0[cc].w);
                    acc1[cc].x = fd2(xb[d2], q.x, acc1[cc].x);
                    acc1[cc].y = fd2(xb[d2], q.y, acc1[cc].y);
                    acc1[cc].z = fd2(xb[d2], q.z, acc1[cc].z);
                    acc1[cc].w = fd2(xb[d2], q.w, acc1[cc].w);
                }
            }
        } else {
            unsigned uhp0[5][2], uhp1[5][2];
            float wgt0[5], wgt1[5];
            float s0 = 0.f, s1 = 0.f;
#pragma unroll
            for (int cc = 0; cc < 5; ++cc) {
                const uint4* wq = &wlds[(j * C_ + cbase + cc) * 16];
                float4 u0 = make_float4(0.f, 0.f, 0.f, 0.f);
                float4 u1 = make_float4(0.f, 0.f, 0.f, 0.f);
#pragma unroll
                for (int d2 = 0; d2 < 4; ++d2) {
                    const uint4 q = wq[d2 * 4 + eq];
                    u0.x = fd2(xa[d2], q.x, u0.x);
                    u0.y = fd2(xa[d2], q.y, u0.y);
                    u0.z = fd2(xa[d2], q.z, u0.z);
                    u0.w = fd2(xa[d2], q.w, u0.w);
                    u1.x = fd2(xb[d2], q.x, u1.x);
                    u1.y = fd2(xb[d2], q.y, u1.y);
                    u1.z = fd2(xb[d2], q.z, u1.z);
                    u1.w = fd2(xb[d2], q.w, u1.w);
                }
                const unsigned up00 = pkh(u0.x, u0.y), up01 = pkh(u0.z, u0.w);
                const unsigned up10 = pkh(u1.x, u1.y), up11 = pkh(u1.z, u1.w);
                float t0 = fd2(up00, vcp0[cc][0], fd2(up01, vcp0[cc][1], 0.f));
                t0 += __shfl_xor(t0, 1); t0 += __shfl_xor(t0, 2);
                float t1 = fd2(up10, vcp1[cc][0], fd2(up11, vcp1[cc][1], 0.f));
                t1 += __shfl_xor(t1, 1); t1 += __shfl_xor(t1, 2);
                wgt0[cc] = __expf(t0); s0 += wgt0[cc];
                wgt1[cc] = __expf(t1); s1 += wgt1[cc];
                uhp0[cc][0] = up00; uhp0[cc][1] = up01;
                uhp1[cc][0] = up10; uhp1[cc][1] = up11;
            }
            // exchange the 5-class exp-sums with the other c-group
            if (eq == 0) {
                xch[j & 1][cg][h][bl][0] = s0;
                xch[j & 1][cg][h][bl][1] = s1;
            }
            __syncthreads();
            const float i0 = 1.f / (s0 + xch[j & 1][cg ^ 1][h][bl][0]);
            const float i1 = 1.f / (s1 + xch[j & 1][cg ^ 1][h][bl][1]);
#pragma unroll
            for (int cc = 0; cc < 5; ++cc) {
                const float g0 = wgt0[cc] * i0, g1 = wgt1[cc] * i1;
                acc0[cc].x = fmaf(g0, hlo(uhp0[cc][0]), acc0[cc].x);
                acc0[cc].y = fmaf(g0, hhi(uhp0[cc][0]), acc0[cc].y);
                acc0[cc].z = fmaf(g0, hlo(uhp0[cc][1]), acc0[cc].z);
                acc0[cc].w = fmaf(g0, hhi(uhp0[cc][1]), acc0[cc].w);
                acc1[cc].x = fmaf(g1, hlo(uhp1[cc][0]), acc1[cc].x);
                acc1[cc].y = fmaf(g1, hhi(uhp1[cc][0]), acc1[cc].y);
                acc1[cc].z = fmaf(g1, hlo(uhp1[cc][1]), acc1[cc].z);
                acc1[cc].w = fmaf(g1, hhi(uhp1[cc][1]), acc1[cc].w);
            }
        }
    }

    // ---- direct fp16 partial store: partial[b][slot][c*8 + eq*2] ----
    const float fold = UNIFORM ? 0.1f : 1.f;   // softmax(0) = 1/10 folded out
#pragma unroll
    for (int cc = 0; cc < 5; ++cc) {
        const int c = cbase + cc;
        *(uint2*)(partial + ((size_t)b0 * NSLOT_ + blk) * PROW_ + c * 8 + eq * 2) =
            make_uint2(hpack(acc0[cc].x * fold, acc0[cc].y * fold),
                       hpack(acc0[cc].z * fold, acc0[cc].w * fold));
        *(uint2*)(partial + ((size_t)b1 * NSLOT_ + blk) * PROW_ + c * 8 + eq * 2) =
            make_uint2(hpack(acc1[cc].x * fold, acc1[cc].y * fold),
                       hpack(acc1[cc].z * fold, acc1[cc].w * fold));
    }
}

// Reduce stage A: 512 blocks = (b, sg); sum 128 slots -> sub[b][sg][160] f32.
// 256 thr: (sc: 8 chunks of 16 slots) x (col4: 20 uint4 cols). Coalesced.
__global__ __launch_bounds__(256) void caps_redA(
    const unsigned* __restrict__ partial, float* __restrict__ sub)
{
    const int b  = (int)blockIdx.x >> 3;
    const int sg = (int)blockIdx.x & 7;
    const int tid = (int)threadIdx.x;
    const int sc   = tid >> 5;          // 0..7
    const int col4 = tid & 31;          // active < 20
    __shared__ float red[8][20][8];
    if (col4 < 20) {
        float s[8];
#pragma unroll
        for (int p = 0; p < 8; ++p) s[p] = 0.f;
        const int slot0 = sg * (NSLOT_ / NSG_) + sc * 16;
        const uint4* base = (const uint4*)(partial +
            ((size_t)b * NSLOT_ + slot0) * PROW_) + col4;
#pragma unroll 4
        for (int k = 0; k < 16; ++k) {
            const uint4 q = base[k * (PROW_ / 4)];
            const float2 f0 = hunpack(q.x), f1 = hunpack(q.y);
            const float2 f2 = hunpack(q.z), f3 = hunpack(q.w);
            s[0] += f0.x; s[1] += f0.y; s[2] += f1.x; s[3] += f1.y;
            s[4] += f2.x; s[5] += f2.y; s[6] += f3.x; s[7] += f3.y;
        }
#pragma unroll
        for (int p = 0; p < 8; ++p) red[sc][col4][p] = s[p];
    }
    __syncthreads();
    if (tid < 160) {
        const int c4 = tid >> 3, p = tid & 7;
        float s = 0.f;
#pragma unroll
        for (int ch = 0; ch < 8; ++ch) s += red[ch][c4][p];
        sub[((size_t)b * NSG_ + sg) * (C_ * E_) + c4 * 8 + p] = s;
    }
}

// Reduce stage B: 64 blocks (one per b): sum 8 subpartials, squash, update.
// mode: 0 = v_cum = v, 1 = v_cum += v, 2 = out = v
__global__ __launch_bounds__(192) void caps_redB(
    const float* __restrict__ sub, float* __restrict__ v_cum,
    float* __restrict__ out, int mode)
{
    const int b = (int)blockIdx.x;
    const int tid = (int)threadIdx.x;
    if (tid >= C_ * E_) return;
    float s = 0.f;
#pragma unroll
    for (int sg = 0; sg < NSG_; ++sg)
        s += sub[((size_t)b * NSG_ + sg) * (C_ * E_) + tid];
    float p = s * s;                     // sum over the 16 e lanes of this c
    p += __shfl_xor(p, 1); p += __shfl_xor(p, 2);
    p += __shfl_xor(p, 4); p += __shfl_xor(p, 8);
    const float sc = (p / (1.f + p)) * rsqrtf(p + EPS_);
    const float v = sc * s;
    const int o = b * (C_ * E_) + tid;
    if (mode == 2)      out[o] = v;
    else if (mode == 0) v_cum[o] = v;
    else                v_cum[o] += v;
}

extern "C" void kernel_launch(void* const* d_in, const int* in_sizes, int n_in,
                              void* d_out, int out_size, void* d_ws, size_t ws_size,
                              hipStream_t stream) {
    const float* x = (const float*)d_in[0];
    const float* W = (const float*)d_in[1];
    float* out = (float*)d_out;

    unsigned* partial = (unsigned*)d_ws;   // 64*1024*80*4 = 20.97 MB
    float* sub = (float*)((char*)d_ws +
        (size_t)B_ * NSLOT_ * PROW_ * sizeof(unsigned));          // 327 KB
    float* v_cum = sub + (size_t)B_ * NSG_ * C_ * E_;             // 40 KB

    for (int t = 0; t < 3; ++t) {
        if (t == 0)
            caps_pass<true ><<<dim3(NBLK_), 256, 0, stream>>>(x, W, v_cum, partial);
        else
            caps_pass<false><<<dim3(NBLK_), 256, 0, stream>>>(x, W, v_cum, partial);
        caps_redA<<<dim3(B_ * NSG_), 256, 0, stream>>>(partial, sub);
        caps_redB<<<dim3(B_), 192, 0, stream>>>(sub, v_cum, out, t);
    }
}